// Round 6
// baseline (1025.947 us; speedup 1.0000x reference)
//
#include <hip/hip_runtime.h>
#include <math.h>
#include <stdint.h>

#define BB 128   // batch
#define SS 128   // seq len
#define EE 300   // embed dim
#define HH 256   // per-direction hidden
#define G4 1024  // 4*HH gate width
#define TT 16    // tagset
#define NBG 32   // batch groups of 4
#define NEGV -10000.0f
#define START_TAG 14
#define STOP_TAG 15

typedef float f32x4 __attribute__((ext_vector_type(4)));

__device__ __forceinline__ float sigm(float x) { return 1.0f / (1.0f + expf(-x)); }

__device__ __forceinline__ float4 shfl_xor4(float4 v, int m) {
  float4 r;
  r.x = __shfl_xor(v.x, m); r.y = __shfl_xor(v.y, m);
  r.z = __shfl_xor(v.z, m); r.w = __shfl_xor(v.w, m);
  return r;
}
__device__ __forceinline__ void add4(float4& a, const float4& b) {
  a.x += b.x; a.y += b.y; a.z += b.z; a.w += b.w;
}

// LLC-coherent vector load: sc0+sc1 bypass L1/L2 -> device coherent point.
// Proven class (R5 passed twice against relaxed agent-scope atomic stores).
__device__ __forceinline__ void load_f8_llc(const float* p, f32x4& a, f32x4& b) {
  asm volatile("global_load_dwordx4 %0, %2, off sc0 sc1\n\t"
               "global_load_dwordx4 %1, %2, off offset:16 sc0 sc1\n\t"
               "s_waitcnt vmcnt(0)"
               : "=&v"(a), "=&v"(b) : "v"(p) : "memory");
}

// Publish (h, stamp) as ONE 8B relaxed agent-scope atomic store: payload is
// self-validating, so no producer-side ordering (fence/drain/tag) is needed.
__device__ __forceinline__ void store_pair_llc(float2* p, float h, int stamp) {
  uint64_t bits = ((uint64_t)(uint32_t)stamp << 32) | (uint64_t)__float_as_uint(h);
  __hip_atomic_store((uint64_t*)p, bits, __ATOMIC_RELAXED, __HIP_MEMORY_SCOPE_AGENT);
}

// ---------------- prep: weight transposes + bias folding ----------------
__global__ void k_prep(const float* __restrict__ Wih_f, const float* __restrict__ Whh_f,
                       const float* __restrict__ bih_f, const float* __restrict__ bhh_f,
                       const float* __restrict__ Wih_b, const float* __restrict__ Whh_b,
                       const float* __restrict__ bih_b, const float* __restrict__ bhh_b,
                       float* __restrict__ WihT, float* __restrict__ Whh4,
                       float* __restrict__ bsum) {
  int id = blockIdx.x * blockDim.x + threadIdx.x;
  const int N1 = 2 * EE * G4;
  const int N2 = 2 * HH * G4;
  const int N3 = 2 * G4;
  if (id < N1) {
    int d = id / (EE * G4); int r = id % (EE * G4);
    int e = r / G4; int j = r % G4;
    const float* W = d ? Wih_b : Wih_f;
    WihT[id] = W[j * EE + e];
  } else if (id < N1 + N2) {
    int t = id - N1;
    int d = t / (HH * G4); int r = t % (HH * G4);
    int k = r / G4; int q = r % G4; int u = q >> 2; int g = q & 3;
    const float* W = d ? Whh_b : Whh_f;
    Whh4[t] = W[(g * HH + u) * HH + k];
  } else if (id < N1 + N2 + N3) {
    int t = id - N1 - N2;
    int d = t / G4; int j = t % G4;
    bsum[t] = d ? (bih_b[j] + bhh_b[j]) : (bih_f[j] + bhh_f[j]);
  }
}

// ---------------- input projection GEMM (gathered) ----------------
__global__ void k_xproj(const int* __restrict__ sent, const float* __restrict__ emb,
                        const float* __restrict__ WihT, const float* __restrict__ bsum,
                        float4* __restrict__ xp4) {
  __shared__ float xs[16][EE];
  __shared__ int idxs[16];
  int blk = blockIdx.x;
  int d = blk >> 10;
  int tile = blk & 1023;
  int tid = threadIdx.x;
  if (tid < 16) {
    int sb = tile * 16 + tid;
    int s = sb >> 7, b = sb & 127;
    idxs[tid] = sent[b * SS + s];
  }
  __syncthreads();
  for (int t = tid; t < 16 * EE; t += 256) {
    int i = t / EE, e = t % EE;
    xs[i][e] = emb[(size_t)idxs[i] * EE + e];
  }
  __syncthreads();

  const float* WT = WihT + (size_t)d * EE * G4;
  float acc0[16], acc1[16], acc2[16], acc3[16];
#pragma unroll
  for (int i = 0; i < 16; ++i) { acc0[i] = 0.f; acc1[i] = 0.f; acc2[i] = 0.f; acc3[i] = 0.f; }

  for (int e = 0; e < EE; ++e) {
    const float* row = WT + (size_t)e * G4;
    float w0 = row[tid];
    float w1 = row[tid + 256];
    float w2 = row[tid + 512];
    float w3 = row[tid + 768];
#pragma unroll
    for (int i = 0; i < 16; ++i) {
      float x = xs[i][e];
      acc0[i] += w0 * x; acc1[i] += w1 * x; acc2[i] += w2 * x; acc3[i] += w3 * x;
    }
  }
  float b0 = bsum[d * G4 + tid];
  float b1 = bsum[d * G4 + tid + 256];
  float b2 = bsum[d * G4 + tid + 512];
  float b3 = bsum[d * G4 + tid + 768];
#pragma unroll
  for (int i = 0; i < 16; ++i) {
    int sb = tile * 16 + i;
    int s = sb >> 7, b = sb & 127;
    xp4[(((size_t)d * SS + s) * BB + b) * HH + tid] =
        make_float4(acc0[i] + b0, acc1[i] + b1, acc2[i] + b2, acc3[i] + b3);
  }
}

// ---------------- recurrent BiLSTM: dual-chain interleave, stamped pairs ----------------
// grid 256: bgrp = blk>>3 (4 batches), sl = blk&7 (32 hidden units).
// Each block runs BOTH directions for its (bgrp, sl); the two chains' compute
// phases hide each other's LLC publish->consume latency.
// hpair layout: [d][slot3][bgrp][b4][k256] of float2 (h, stamp); stamp of step
// t is t+1, slot = t%3. Self-validating: consumers poll their own pairs.
__global__ __launch_bounds__(256, 1) void k_recur(
    const float4* __restrict__ xp4, const float4* __restrict__ Wg,
    const float* __restrict__ Wout, const float* __restrict__ h0,
    const float* __restrict__ c0, float2* __restrict__ hpair,
    float* __restrict__ featsP) {
  __shared__ __align__(16) float ldsF[4 * 288];  // fwd h staging, kc-swizzled
  __shared__ __align__(16) float ldsB[4 * 288];  // bwd h staging
  __shared__ float hlocF[4 * 33], hlocB[4 * 33];
  __shared__ float WoF[16 * 33], WoB[16 * 33];

  int blk = blockIdx.x;
  int bgrp = blk >> 3, sl = blk & 7;
  int tid = threadIdx.x;
  int u = tid >> 3, kc = tid & 7;
  int uglob = sl * 32 + u;
  int b_own = (kc & 1) * 2 + ((kc >> 1) & 1);
  int bglob = bgrp * 4 + b_own;
  bool up0 = kc & 1, up1 = kc & 2;

  for (int i = tid; i < 16 * 32; i += 256) {
    int t = i >> 5, uu = i & 31;
    WoF[t * 33 + uu] = Wout[t * 512 + sl * 32 + uu];
    WoB[t * 33 + uu] = Wout[t * 512 + 256 + sl * 32 + uu];
  }

  // Whh slices (both dirs) -> registers: w[kk] = Whh4[d][kc*32+kk][uglob]
  float4 wf[32], wb[32];
  {
    const float4* Wd = Wg + (size_t)(kc * 32) * HH + uglob;
#pragma unroll
    for (int kk = 0; kk < 32; ++kk) wf[kk] = Wd[(size_t)kk * HH];
    Wd += (size_t)HH * HH;
#pragma unroll
    for (int kk = 0; kk < 32; ++kk) wb[kk] = Wd[(size_t)kk * HH];
  }
  float cf = c0[(size_t)(0 * BB + bglob) * HH + uglob];
  float cb = c0[(size_t)(1 * BB + bglob) * HH + uglob];

  // staging split: thread loads (sb, k4..k4+3)
  int sb = tid >> 6;
  int sk = (tid & 63) * 4;
  float* dstF = ldsF + sb * 288 + (sk >> 5) * 36 + (sk & 31);
  float* dstB = ldsB + sb * 288 + (sk >> 5) * 36 + (sk & 31);

  for (int step = 0; step < SS; ++step) {
    int s_f = step, s_b = SS - 1 - step;
    int slot_w = step % 3;
    int slot_r = (step + 2) % 3;

    // prefetch both gate-input vecs (h-independent)
    float4 xgf = xp4[(((size_t)0 * SS + s_f) * BB + bglob) * HH + uglob];
    float4 xgb = xp4[(((size_t)1 * SS + s_b) * BB + bglob) * HH + uglob];

    // ---- stage fwd h(step-1) ----
    if (step == 0) {
      const float* ps = h0 + (size_t)(bgrp * 4 + sb) * HH + sk;
      *(f32x4*)dstF = *(const f32x4*)ps;
    } else {
      const float2* ps = hpair + (((size_t)(0 * 3 + slot_r) * NBG + bgrp) * 4 + sb) * HH + sk;
      f32x4 a, b;
      for (;;) {
        load_f8_llc((const float*)ps, a, b);
        if (__float_as_int(a[1]) == step && __float_as_int(a[3]) == step &&
            __float_as_int(b[1]) == step && __float_as_int(b[3]) == step) break;
      }
      dstF[0] = a[0]; dstF[1] = a[2]; dstF[2] = b[0]; dstF[3] = b[2];
    }
    __syncthreads();

    // ---- fwd compute ----
    {
      float4 a0 = make_float4(0.f, 0.f, 0.f, 0.f), a1 = a0, a2 = a0, a3 = a0;
#pragma unroll
      for (int kk4 = 0; kk4 < 8; ++kk4) {
        f32x4 h0v = *(const f32x4*)&ldsF[0 * 288 + kc * 36 + kk4 * 4];
        f32x4 h1v = *(const f32x4*)&ldsF[1 * 288 + kc * 36 + kk4 * 4];
        f32x4 h2v = *(const f32x4*)&ldsF[2 * 288 + kc * 36 + kk4 * 4];
        f32x4 h3v = *(const f32x4*)&ldsF[3 * 288 + kc * 36 + kk4 * 4];
#pragma unroll
        for (int j = 0; j < 4; ++j) {
          float4 w = wf[kk4 * 4 + j];
          a0.x += w.x * h0v[j]; a0.y += w.y * h0v[j]; a0.z += w.z * h0v[j]; a0.w += w.w * h0v[j];
          a1.x += w.x * h1v[j]; a1.y += w.y * h1v[j]; a1.z += w.z * h1v[j]; a1.w += w.w * h1v[j];
          a2.x += w.x * h2v[j]; a2.y += w.y * h2v[j]; a2.z += w.z * h2v[j]; a2.w += w.w * h2v[j];
          a3.x += w.x * h3v[j]; a3.y += w.y * h3v[j]; a3.z += w.z * h3v[j]; a3.w += w.w * h3v[j];
        }
      }
      // reduce-scatter over kc with lane duplication (kc and kc^4 share b_own)
      float4 sA = up0 ? a0 : a2; float4 rA = shfl_xor4(sA, 1);
      float4 sB = up0 ? a1 : a3; float4 rB = shfl_xor4(sB, 1);
      float4 kA = up0 ? a2 : a0; add4(kA, rA);
      float4 kB = up0 ? a3 : a1; add4(kB, rB);
      float4 sC = up1 ? kA : kB; float4 rC = shfl_xor4(sC, 2);
      float4 kD = up1 ? kB : kA; add4(kD, rC);
      float4 rD = shfl_xor4(kD, 4); add4(kD, rD);

      float ii = kD.x + xgf.x, ff = kD.y + xgf.y, gg = kD.z + xgf.z, oo = kD.w + xgf.w;
      cf = sigm(ff) * cf + sigm(ii) * tanhf(gg);
      float hn = sigm(oo) * tanhf(cf);
      if (kc < 4) {
        store_pair_llc(&hpair[(((size_t)(0 * 3 + slot_w) * NBG + bgrp) * 4 + b_own) * HH + uglob],
                       hn, step + 1);
        hlocF[b_own * 33 + u] = hn;
      }
    }
    __syncthreads();

    // ---- feats fwd + stage bwd h(step-1) ----
    {
      int b2 = tid >> 6, t = (tid >> 2) & 15, q = tid & 3;
      float p = 0.f;
#pragma unroll
      for (int u8 = 0; u8 < 8; ++u8)
        p += hlocF[b2 * 33 + q * 8 + u8] * WoF[t * 33 + q * 8 + u8];
      p += __shfl_xor(p, 1); p += __shfl_xor(p, 2);
      if (q == 0)
        featsP[(((size_t)(0 * 8 + sl) * BB + bgrp * 4 + b2) * SS + s_f) * TT + t] = p;
    }
    if (step == 0) {
      const float* ps = h0 + ((size_t)BB + bgrp * 4 + sb) * HH + sk;
      *(f32x4*)dstB = *(const f32x4*)ps;
    } else {
      const float2* ps = hpair + (((size_t)(1 * 3 + slot_r) * NBG + bgrp) * 4 + sb) * HH + sk;
      f32x4 a, b;
      for (;;) {
        load_f8_llc((const float*)ps, a, b);
        if (__float_as_int(a[1]) == step && __float_as_int(a[3]) == step &&
            __float_as_int(b[1]) == step && __float_as_int(b[3]) == step) break;
      }
      dstB[0] = a[0]; dstB[1] = a[2]; dstB[2] = b[0]; dstB[3] = b[2];
    }
    __syncthreads();

    // ---- bwd compute ----
    {
      float4 a0 = make_float4(0.f, 0.f, 0.f, 0.f), a1 = a0, a2 = a0, a3 = a0;
#pragma unroll
      for (int kk4 = 0; kk4 < 8; ++kk4) {
        f32x4 h0v = *(const f32x4*)&ldsB[0 * 288 + kc * 36 + kk4 * 4];
        f32x4 h1v = *(const f32x4*)&ldsB[1 * 288 + kc * 36 + kk4 * 4];
        f32x4 h2v = *(const f32x4*)&ldsB[2 * 288 + kc * 36 + kk4 * 4];
        f32x4 h3v = *(const f32x4*)&ldsB[3 * 288 + kc * 36 + kk4 * 4];
#pragma unroll
        for (int j = 0; j < 4; ++j) {
          float4 w = wb[kk4 * 4 + j];
          a0.x += w.x * h0v[j]; a0.y += w.y * h0v[j]; a0.z += w.z * h0v[j]; a0.w += w.w * h0v[j];
          a1.x += w.x * h1v[j]; a1.y += w.y * h1v[j]; a1.z += w.z * h1v[j]; a1.w += w.w * h1v[j];
          a2.x += w.x * h2v[j]; a2.y += w.y * h2v[j]; a2.z += w.z * h2v[j]; a2.w += w.w * h2v[j];
          a3.x += w.x * h3v[j]; a3.y += w.y * h3v[j]; a3.z += w.z * h3v[j]; a3.w += w.w * h3v[j];
        }
      }
      float4 sA = up0 ? a0 : a2; float4 rA = shfl_xor4(sA, 1);
      float4 sB = up0 ? a1 : a3; float4 rB = shfl_xor4(sB, 1);
      float4 kA = up0 ? a2 : a0; add4(kA, rA);
      float4 kB = up0 ? a3 : a1; add4(kB, rB);
      float4 sC = up1 ? kA : kB; float4 rC = shfl_xor4(sC, 2);
      float4 kD = up1 ? kB : kA; add4(kD, rC);
      float4 rD = shfl_xor4(kD, 4); add4(kD, rD);

      float ii = kD.x + xgb.x, ff = kD.y + xgb.y, gg = kD.z + xgb.z, oo = kD.w + xgb.w;
      cb = sigm(ff) * cb + sigm(ii) * tanhf(gg);
      float hn = sigm(oo) * tanhf(cb);
      if (kc < 4) {
        store_pair_llc(&hpair[(((size_t)(1 * 3 + slot_w) * NBG + bgrp) * 4 + b_own) * HH + uglob],
                       hn, step + 1);
        hlocB[b_own * 33 + u] = hn;
      }
    }
    __syncthreads();

    // ---- feats bwd (no trailing barrier: ldsF rewrite is 2+ barriers away) ----
    {
      int b2 = tid >> 6, t = (tid >> 2) & 15, q = tid & 3;
      float p = 0.f;
#pragma unroll
      for (int u8 = 0; u8 < 8; ++u8)
        p += hlocB[b2 * 33 + q * 8 + u8] * WoB[t * 33 + q * 8 + u8];
      p += __shfl_xor(p, 1); p += __shfl_xor(p, 2);
      if (q == 0)
        featsP[(((size_t)(1 * 8 + sl) * BB + bgrp * 4 + b2) * SS + s_b) * TT + t] = p;
    }
  }
}

// ---------------- feats slice reduction ----------------
__global__ void k_fsum(const float* __restrict__ featsP, float* __restrict__ featsF) {
  int b = blockIdx.x;
  int tid = threadIdx.x;
  float acc[8];
#pragma unroll
  for (int j = 0; j < 8; ++j) acc[j] = 0.f;
  for (int dsl = 0; dsl < 16; ++dsl) {
    const float* fp = featsP + ((size_t)dsl * BB + b) * (SS * TT);
#pragma unroll
    for (int j = 0; j < 8; ++j) acc[j] += fp[j * 256 + tid];
  }
  float* fo = featsF + (size_t)b * (SS * TT);
#pragma unroll
  for (int j = 0; j < 8; ++j) fo[j * 256 + tid] = acc[j];
}

// ---------------- Viterbi ----------------
__global__ void k_viterbi(const float* __restrict__ featsF, const float* __restrict__ b_out,
                          const float* __restrict__ trans, float* __restrict__ out,
                          unsigned char* __restrict__ bp) {
  __shared__ float tr[TT * TT];
  int tid = threadIdx.x;
  if (tid < TT * TT) tr[tid] = trans[tid];
  __syncthreads();

  int bg = tid >> 4;
  int next = tid & 15;
  int b = blockIdx.x * 16 + bg;
  float fv = (next == START_TAG) ? 0.0f : NEGV;
  float bo = b_out[next];
  const float* fF = featsF + (size_t)b * SS * TT;

  for (int s = 0; s < SS; ++s) {
    float best = -INFINITY; int arg = 0;
#pragma unroll
    for (int prev = 0; prev < TT; ++prev) {
      float fvp = __shfl(fv, prev, 16);
      float cand = fvp + tr[next * TT + prev];
      if (cand > best) { best = cand; arg = prev; }
    }
    float feat = fF[s * TT + next] + bo;
    fv = best + feat;
    bp[((size_t)b * SS + s) * TT + next] = (unsigned char)arg;
  }

  float bv = fv + tr[STOP_TAG * TT + next];
  int bi = next;
#pragma unroll
  for (int off = 8; off; off >>= 1) {
    float ov = __shfl_down(bv, off, 16);
    int oi = __shfl_down(bi, off, 16);
    if (ov > bv || (ov == bv && oi < bi)) { bv = ov; bi = oi; }
  }
  if (next == 0) {
    out[b] = bv;
    int tag = bi;
    float* po = out + BB + (size_t)b * SS;
    for (int s = SS - 1; s >= 0; --s) {
      po[s] = (float)tag;
      tag = bp[((size_t)b * SS + s) * TT + tag];
    }
  }
}

// ---------------- host ----------------
extern "C" void kernel_launch(void* const* d_in, const int* in_sizes, int n_in,
                              void* d_out, int out_size, void* d_ws, size_t ws_size,
                              hipStream_t stream) {
  const int*   sent  = (const int*)d_in[0];
  const float* emb   = (const float*)d_in[1];
  const float* Wih_f = (const float*)d_in[2];
  const float* Whh_f = (const float*)d_in[3];
  const float* bih_f = (const float*)d_in[4];
  const float* bhh_f = (const float*)d_in[5];
  const float* Wih_b = (const float*)d_in[6];
  const float* Whh_b = (const float*)d_in[7];
  const float* bih_b = (const float*)d_in[8];
  const float* bhh_b = (const float*)d_in[9];
  const float* Wout  = (const float*)d_in[10];
  const float* b_out = (const float*)d_in[11];
  const float* trans = (const float*)d_in[12];
  const float* h0    = (const float*)d_in[13];
  const float* c0    = (const float*)d_in[14];

  float* ws = (float*)d_ws;
  size_t off = 0;
  float* xproj  = ws + off; off += (size_t)2 * SS * BB * G4;        // 33,554,432 fl
  float* WihT   = ws + off; off += (size_t)2 * EE * G4;             //    614,400
  float* Whh4   = ws + off; off += (size_t)2 * HH * G4;             //    524,288
  float* bsum   = ws + off; off += (size_t)2 * G4;                  //      2,048
  float* featsP = ws + off; off += (size_t)16 * BB * SS * TT;       //  4,194,304
  float* featsF = ws + off; off += (size_t)BB * SS * TT;            //    262,144
  float* hpairf = ws + off; off += (size_t)2 * 3 * NBG * 4 * HH * 2; //   393,216 (float2 pairs)
  unsigned char* bp = (unsigned char*)(ws + off);                   //    262,144 B

  const int NPREP = 2 * EE * G4 + 2 * HH * G4 + 2 * G4;
  k_prep<<<(NPREP + 255) / 256, 256, 0, stream>>>(Wih_f, Whh_f, bih_f, bhh_f,
                                                  Wih_b, Whh_b, bih_b, bhh_b,
                                                  WihT, Whh4, bsum);
  k_xproj<<<2048, 256, 0, stream>>>(sent, emb, WihT, bsum, (float4*)xproj);

  {
    const float4* xp4c = (const float4*)xproj;
    const float4* Wgc  = (const float4*)Whh4;
    float2* hpair = (float2*)hpairf;
    void* kargs[] = {(void*)&xp4c, (void*)&Wgc, (void*)&Wout, (void*)&h0,
                     (void*)&c0, (void*)&hpair, (void*)&featsP};
    hipError_t e = hipLaunchCooperativeKernel(k_recur, dim3(256), dim3(256),
                                              kargs, 0, stream);
    if (e != hipSuccess) {
      k_recur<<<256, 256, 0, stream>>>(xp4c, Wgc, Wout, h0, c0, hpair, featsP);
    }
  }

  k_fsum<<<BB, 256, 0, stream>>>(featsP, featsF);
  k_viterbi<<<8, 256, 0, stream>>>(featsF, b_out, trans, (float*)d_out, bp);
}

// Round 7
// 945.335 us; speedup vs baseline: 1.0853x; 1.0853x over previous
//
#include <hip/hip_runtime.h>
#include <math.h>
#include <stdint.h>

#define BB 128   // batch
#define SS 128   // seq len
#define EE 300   // embed dim
#define HH 256   // per-direction hidden
#define G4 1024  // 4*HH gate width
#define TT 16    // tagset
#define NEGV -10000.0f
#define START_TAG 14
#define STOP_TAG 15

typedef float f32x4 __attribute__((ext_vector_type(4)));

__device__ __forceinline__ float sigm(float x) { return 1.0f / (1.0f + expf(-x)); }

__device__ __forceinline__ float4 shfl_xor4(float4 v, int m) {
  float4 r;
  r.x = __shfl_xor(v.x, m); r.y = __shfl_xor(v.y, m);
  r.z = __shfl_xor(v.z, m); r.w = __shfl_xor(v.w, m);
  return r;
}
__device__ __forceinline__ void add4(float4& a, const float4& b) {
  a.x += b.x; a.y += b.y; a.z += b.z; a.w += b.w;
}

// Poll 8 stamped pairs (64B) from the device coherent point (sc0+sc1 bypass
// L1/L2). Same load/store class R5/R6 proved correct on this chip.
__device__ __forceinline__ void load_pairs16(const float* p, f32x4& a, f32x4& b,
                                             f32x4& c, f32x4& d) {
  asm volatile("global_load_dwordx4 %0, %4, off sc0 sc1\n\t"
               "global_load_dwordx4 %1, %4, off offset:16 sc0 sc1\n\t"
               "global_load_dwordx4 %2, %4, off offset:32 sc0 sc1\n\t"
               "global_load_dwordx4 %3, %4, off offset:48 sc0 sc1\n\t"
               "s_waitcnt vmcnt(0)"
               : "=&v"(a), "=&v"(b), "=&v"(c), "=&v"(d) : "v"(p) : "memory");
}

// Publish (h, stamp) as ONE 8B relaxed agent-scope atomic store: payload is
// self-validating; no producer-side drain/tag/fence needed.
__device__ __forceinline__ void store_pair_llc(float2* p, float h, int stamp) {
  uint64_t bits = ((uint64_t)(uint32_t)stamp << 32) | (uint64_t)__float_as_uint(h);
  __hip_atomic_store((uint64_t*)p, bits, __ATOMIC_RELAXED, __HIP_MEMORY_SCOPE_AGENT);
}

// ---------------- prep: weight transposes + bias folding ----------------
__global__ void k_prep(const float* __restrict__ Wih_f, const float* __restrict__ Whh_f,
                       const float* __restrict__ bih_f, const float* __restrict__ bhh_f,
                       const float* __restrict__ Wih_b, const float* __restrict__ Whh_b,
                       const float* __restrict__ bih_b, const float* __restrict__ bhh_b,
                       float* __restrict__ WihT, float* __restrict__ Whh4,
                       float* __restrict__ bsum) {
  int id = blockIdx.x * blockDim.x + threadIdx.x;
  const int N1 = 2 * EE * G4;
  const int N2 = 2 * HH * G4;
  const int N3 = 2 * G4;
  if (id < N1) {
    int d = id / (EE * G4); int r = id % (EE * G4);
    int e = r / G4; int j = r % G4;
    const float* W = d ? Wih_b : Wih_f;
    WihT[id] = W[j * EE + e];
  } else if (id < N1 + N2) {
    int t = id - N1;
    int d = t / (HH * G4); int r = t % (HH * G4);
    int k = r / G4; int q = r % G4; int u = q >> 2; int g = q & 3;
    const float* W = d ? Whh_b : Whh_f;
    Whh4[t] = W[(g * HH + u) * HH + k];
  } else if (id < N1 + N2 + N3) {
    int t = id - N1 - N2;
    int d = t / G4; int j = t % G4;
    bsum[t] = d ? (bih_b[j] + bhh_b[j]) : (bih_f[j] + bhh_f[j]);
  }
}

// ---------------- input projection GEMM (gathered) ----------------
__global__ void k_xproj(const int* __restrict__ sent, const float* __restrict__ emb,
                        const float* __restrict__ WihT, const float* __restrict__ bsum,
                        float4* __restrict__ xp4) {
  __shared__ float xs[16][EE];
  __shared__ int idxs[16];
  int blk = blockIdx.x;
  int d = blk >> 10;
  int tile = blk & 1023;
  int tid = threadIdx.x;
  if (tid < 16) {
    int sb = tile * 16 + tid;
    int s = sb >> 7, b = sb & 127;
    idxs[tid] = sent[b * SS + s];
  }
  __syncthreads();
  for (int t = tid; t < 16 * EE; t += 256) {
    int i = t / EE, e = t % EE;
    xs[i][e] = emb[(size_t)idxs[i] * EE + e];
  }
  __syncthreads();

  const float* WT = WihT + (size_t)d * EE * G4;
  float acc0[16], acc1[16], acc2[16], acc3[16];
#pragma unroll
  for (int i = 0; i < 16; ++i) { acc0[i] = 0.f; acc1[i] = 0.f; acc2[i] = 0.f; acc3[i] = 0.f; }

  for (int e = 0; e < EE; ++e) {
    const float* row = WT + (size_t)e * G4;
    float w0 = row[tid];
    float w1 = row[tid + 256];
    float w2 = row[tid + 512];
    float w3 = row[tid + 768];
#pragma unroll
    for (int i = 0; i < 16; ++i) {
      float x = xs[i][e];
      acc0[i] += w0 * x; acc1[i] += w1 * x; acc2[i] += w2 * x; acc3[i] += w3 * x;
    }
  }
  float b0 = bsum[d * G4 + tid];
  float b1 = bsum[d * G4 + tid + 256];
  float b2 = bsum[d * G4 + tid + 512];
  float b3 = bsum[d * G4 + tid + 768];
#pragma unroll
  for (int i = 0; i < 16; ++i) {
    int sb = tile * 16 + i;
    int s = sb >> 7, b = sb & 127;
    xp4[(((size_t)d * SS + s) * BB + b) * HH + tid] =
        make_float4(acc0[i] + b0, acc1[i] + b1, acc2[i] + b2, acc3[i] + b3);
  }
}

// ---------------- recurrent LSTM: stamped-pair data poll, 1 barrier/step ----------------
// grid 256: blk = d*128 + bg*8 + sl. 256 thr: tid = u*8 + kc.
// h(step) published as (h, step+1) pairs at ring slot step%3. Consumers poll
// the pairs they stage; the pre-compute barrier gates on all 8 slices, which
// transitively orders LDS buffer reuse (double-buffered by step parity).
// Feats for step-1 computed right after the barrier from the stale hloc parity.
__global__ __launch_bounds__(256, 1) void k_recur(
    const float4* __restrict__ xp4, const float4* __restrict__ Wg,
    const float* __restrict__ Wout, const float* __restrict__ h0,
    const float* __restrict__ c0, float2* __restrict__ hpair,
    float* __restrict__ featsP) {
  __shared__ __align__(16) float hsh[2][8 * 288];  // h staging, kc-swizzled, dbuf
  __shared__ float hloc[2][8 * 33];                // h for feats, dbuf
  __shared__ float WoL[16 * 33];                   // Wout slice

  int blk = blockIdx.x;
  int d = blk >> 7;
  int bg = (blk >> 3) & 15;
  int sl = blk & 7;
  int bbase = bg * 8;
  int tid = threadIdx.x;
  int u = tid >> 3, kc = tid & 7;
  int uglob = sl * 32 + u;

  for (int i = tid; i < 16 * 32; i += 256) {
    int t = i >> 5, uu = i & 31;
    WoL[t * 33 + uu] = Wout[t * 512 + d * HH + sl * 32 + uu];
  }

  // Whh slice -> registers: wreg[kk] = Whh4[d][kc*32+kk][uglob] (i,f,g,o)
  float4 wreg[32];
  {
    const float4* Wd = Wg + (size_t)d * (HH * HH) + (size_t)(kc * 32) * HH + uglob;
#pragma unroll
    for (int kk = 0; kk < 32; ++kk) wreg[kk] = Wd[(size_t)kk * HH];
  }
  int b_own = ((kc & 1) << 2) | (kc & 2) | ((kc >> 2) & 1);
  float c_reg = c0[((size_t)d * BB + bbase + b_own) * HH + uglob];
  bool up0 = (kc & 1), up1 = (kc & 2), up2 = (kc & 4);

  // staging: thread handles pairs (b = tid>>5, k = (tid&31)*8 .. +7)
  int sb = tid >> 5;
  int sk = (tid & 31) * 8;
  int ldoff = sb * 288 + (sk >> 5) * 36 + (sk & 31);

  for (int step = 0; step < SS; ++step) {
    int s = d ? (SS - 1 - step) : step;
    int pb = step & 1;
    // prefetch gate-input vec (h-independent); shares the poll's vmcnt wait
    float4 xg = xp4[(((size_t)d * SS + s) * BB + bbase + b_own) * HH + uglob];

    // ---- stage h(step-1): poll own pairs until stamps == step ----
    float* ldst = &hsh[pb][ldoff];
    if (step == 0) {
      const float* ps = h0 + ((size_t)d * BB + bbase) * HH + (tid << 3);
      *(f32x4*)ldst = *(const f32x4*)ps;
      *(f32x4*)(ldst + 4) = *(const f32x4*)(ps + 4);
    } else {
      int slot_r = (step + 2) % 3;
      const float* ps = (const float*)(hpair +
          ((size_t)(slot_r * 2 + d) * BB + bbase + sb) * HH + sk);
      f32x4 p0, p1, p2, p3;
      for (;;) {
        load_pairs16(ps, p0, p1, p2, p3);
        if (__float_as_int(p0[1]) == step && __float_as_int(p0[3]) == step &&
            __float_as_int(p1[1]) == step && __float_as_int(p1[3]) == step &&
            __float_as_int(p2[1]) == step && __float_as_int(p2[3]) == step &&
            __float_as_int(p3[1]) == step && __float_as_int(p3[3]) == step)
          break;
      }
      f32x4 lo, hi;
      lo[0] = p0[0]; lo[1] = p0[2]; lo[2] = p1[0]; lo[3] = p1[2];
      hi[0] = p2[0]; hi[1] = p2[2]; hi[2] = p3[0]; hi[3] = p3[2];
      *(f32x4*)ldst = lo;
      *(f32x4*)(ldst + 4) = hi;
    }
    __syncthreads();   // the ONLY barrier per step

    // ---- feats for step-1 (stale hloc parity, synced by the barrier) ----
    if (step > 0) {
      int b2 = tid >> 5, t = (tid >> 1) & 15, pr = tid & 1;
      int s_prev = d ? (SS - step) : (step - 1);
      float p = 0.f;
#pragma unroll
      for (int q = 0; q < 16; ++q)
        p += hloc[1 - pb][b2 * 33 + pr * 16 + q] * WoL[t * 33 + pr * 16 + q];
      p += __shfl_xor(p, 1);
      if (!pr)
        featsP[(((size_t)(d * 8 + sl) * BB + bbase + b2) * SS + s_prev) * TT + t] = p;
    }

    // ---- gate partials over this thread's 32-k chunk ----
    const float* hb = &hsh[pb][0];
    float4 a[8];
#pragma unroll
    for (int b = 0; b < 8; ++b) a[b] = make_float4(0.f, 0.f, 0.f, 0.f);
#pragma unroll
    for (int kk4 = 0; kk4 < 8; ++kk4) {
      float hvv[8][4];
#pragma unroll
      for (int b = 0; b < 8; ++b)
        *(f32x4*)&hvv[b][0] = *(const f32x4*)&hb[b * 288 + kc * 36 + kk4 * 4];
#pragma unroll
      for (int j = 0; j < 4; ++j) {
        float4 w = wreg[kk4 * 4 + j];
#pragma unroll
        for (int b = 0; b < 8; ++b) {
          float hj = hvv[b][j];
          a[b].x += w.x * hj; a[b].y += w.y * hj;
          a[b].z += w.z * hj; a[b].w += w.w * hj;
        }
      }
    }

    // ---- reduce-scatter over kc (static register indices) ----
#pragma unroll
    for (int j = 0; j < 4; ++j) {
      float4 snd = up0 ? a[j] : a[j + 4];
      float4 rcv = shfl_xor4(snd, 1);
      if (!up0) add4(a[j], rcv); else add4(a[j + 4], rcv);
    }
    float4 v0 = up0 ? a[4] : a[0];
    float4 v1 = up0 ? a[5] : a[1];
    float4 v2 = up0 ? a[6] : a[2];
    float4 v3 = up0 ? a[7] : a[3];
    {
      float4 snd = up1 ? v0 : v2;
      float4 rcv = shfl_xor4(snd, 2);
      if (!up1) add4(v0, rcv); else add4(v2, rcv);
      snd = up1 ? v1 : v3;
      rcv = shfl_xor4(snd, 2);
      if (!up1) add4(v1, rcv); else add4(v3, rcv);
    }
    float4 w0 = up1 ? v2 : v0;
    float4 w1 = up1 ? v3 : v1;
    {
      float4 snd = up2 ? w0 : w1;
      float4 rcv = shfl_xor4(snd, 4);
      if (!up2) add4(w0, rcv); else add4(w1, rcv);
    }
    float4 g4 = up2 ? w1 : w0;

    // ---- nonlinearity + publish (fire-and-forget) ----
    float ii = g4.x + xg.x, ff = g4.y + xg.y, gg = g4.z + xg.z, oo = g4.w + xg.w;
    c_reg = sigm(ff) * c_reg + sigm(ii) * tanhf(gg);
    float hn = sigm(oo) * tanhf(c_reg);

    store_pair_llc(&hpair[((size_t)((step % 3) * 2 + d) * BB + bbase + b_own) * HH + uglob],
                   hn, step + 1);
    hloc[pb][b_own * 33 + u] = hn;
    // no trailing barrier: next step's poll + barrier provide the ordering
  }

  // tail feats for step SS-1 (hloc parity (SS-1)&1 == 1)
  __syncthreads();
  {
    int b2 = tid >> 5, t = (tid >> 1) & 15, pr = tid & 1;
    int s_prev = d ? 0 : (SS - 1);
    float p = 0.f;
#pragma unroll
    for (int q = 0; q < 16; ++q)
      p += hloc[1][b2 * 33 + pr * 16 + q] * WoL[t * 33 + pr * 16 + q];
    p += __shfl_xor(p, 1);
    if (!pr)
      featsP[(((size_t)(d * 8 + sl) * BB + bbase + b2) * SS + s_prev) * TT + t] = p;
  }
}

// ---------------- feats slice reduction ----------------
__global__ void k_fsum(const float* __restrict__ featsP, float* __restrict__ featsF) {
  int b = blockIdx.x;
  int tid = threadIdx.x;
  float acc[8];
#pragma unroll
  for (int j = 0; j < 8; ++j) acc[j] = 0.f;
  for (int dsl = 0; dsl < 16; ++dsl) {
    const float* fp = featsP + ((size_t)dsl * BB + b) * (SS * TT);
#pragma unroll
    for (int j = 0; j < 8; ++j) acc[j] += fp[j * 256 + tid];
  }
  float* fo = featsF + (size_t)b * (SS * TT);
#pragma unroll
  for (int j = 0; j < 8; ++j) fo[j * 256 + tid] = acc[j];
}

// ---------------- Viterbi (backpointers in LDS) ----------------
__global__ void k_viterbi(const float* __restrict__ featsF, const float* __restrict__ b_out,
                          const float* __restrict__ trans, float* __restrict__ out) {
  __shared__ float tr[TT * TT];
  __shared__ unsigned char bpl[16][SS][TT];   // 32 KB
  int tid = threadIdx.x;
  if (tid < TT * TT) tr[tid] = trans[tid];
  __syncthreads();

  int bg = tid >> 4;
  int next = tid & 15;
  int b = blockIdx.x * 16 + bg;
  float fv = (next == START_TAG) ? 0.0f : NEGV;
  float bo = b_out[next];
  const float* fF = featsF + (size_t)b * SS * TT;

  for (int s = 0; s < SS; ++s) {
    float best = -INFINITY; int arg = 0;
#pragma unroll
    for (int prev = 0; prev < TT; ++prev) {
      float fvp = __shfl(fv, prev, 16);
      float cand = fvp + tr[next * TT + prev];
      if (cand > best) { best = cand; arg = prev; }
    }
    float feat = fF[s * TT + next] + bo;
    fv = best + feat;
    bpl[bg][s][next] = (unsigned char)arg;
  }

  float bv = fv + tr[STOP_TAG * TT + next];
  int bi = next;
#pragma unroll
  for (int off = 8; off; off >>= 1) {
    float ov = __shfl_down(bv, off, 16);
    int oi = __shfl_down(bi, off, 16);
    if (ov > bv || (ov == bv && oi < bi)) { bv = ov; bi = oi; }
  }
  if (next == 0) {
    out[b] = bv;
    int tag = bi;
    float* po = out + BB + (size_t)b * SS;
    for (int s = SS - 1; s >= 0; --s) {
      po[s] = (float)tag;
      tag = bpl[bg][s][tag];
    }
  }
}

// ---------------- host ----------------
extern "C" void kernel_launch(void* const* d_in, const int* in_sizes, int n_in,
                              void* d_out, int out_size, void* d_ws, size_t ws_size,
                              hipStream_t stream) {
  const int*   sent  = (const int*)d_in[0];
  const float* emb   = (const float*)d_in[1];
  const float* Wih_f = (const float*)d_in[2];
  const float* Whh_f = (const float*)d_in[3];
  const float* bih_f = (const float*)d_in[4];
  const float* bhh_f = (const float*)d_in[5];
  const float* Wih_b = (const float*)d_in[6];
  const float* Whh_b = (const float*)d_in[7];
  const float* bih_b = (const float*)d_in[8];
  const float* bhh_b = (const float*)d_in[9];
  const float* Wout  = (const float*)d_in[10];
  const float* b_out = (const float*)d_in[11];
  const float* trans = (const float*)d_in[12];
  const float* h0    = (const float*)d_in[13];
  const float* c0    = (const float*)d_in[14];

  float* ws = (float*)d_ws;
  size_t off = 0;
  float* xproj  = ws + off; off += (size_t)2 * SS * BB * G4;          // 33,554,432 fl
  float* WihT   = ws + off; off += (size_t)2 * EE * G4;               //    614,400
  float* Whh4   = ws + off; off += (size_t)2 * HH * G4;               //    524,288
  float* bsum   = ws + off; off += (size_t)2 * G4;                    //      2,048
  float* featsP = ws + off; off += (size_t)16 * BB * SS * TT;         //  4,194,304
  float* featsF = ws + off; off += (size_t)BB * SS * TT;              //    262,144
  float* hpairf = ws + off; off += (size_t)3 * 2 * BB * HH * 2;       //    393,216

  const int NPREP = 2 * EE * G4 + 2 * HH * G4 + 2 * G4;
  k_prep<<<(NPREP + 255) / 256, 256, 0, stream>>>(Wih_f, Whh_f, bih_f, bhh_f,
                                                  Wih_b, Whh_b, bih_b, bhh_b,
                                                  WihT, Whh4, bsum);
  k_xproj<<<2048, 256, 0, stream>>>(sent, emb, WihT, bsum, (float4*)xproj);

  {
    const float4* xp4c = (const float4*)xproj;
    const float4* Wgc  = (const float4*)Whh4;
    float2* hpair = (float2*)hpairf;
    void* kargs[] = {(void*)&xp4c, (void*)&Wgc, (void*)&Wout, (void*)&h0,
                     (void*)&c0, (void*)&hpair, (void*)&featsP};
    hipError_t e = hipLaunchCooperativeKernel(k_recur, dim3(256), dim3(256),
                                              kargs, 0, stream);
    if (e != hipSuccess) {
      k_recur<<<256, 256, 0, stream>>>(xp4c, Wgc, Wout, h0, c0, hpair, featsP);
    }
  }

  k_fsum<<<BB, 256, 0, stream>>>(featsP, featsF);
  k_viterbi<<<8, 256, 0, stream>>>(featsF, b_out, trans, (float*)d_out);
}